// Round 1
// baseline (246.971 us; speedup 1.0000x reference)
//
#include <hip/hip_runtime.h>
#include <math.h>

// Peak biquad (DF2T) over (16, 2, 1<<20) fp32.
//
// R2 (previous best, 80us kernel @2.5TB/s): latency-bound. Little's law:
// 2529 GB/s * ~375ns  =>  only ~3.7KB outstanding loads per CU. Causes:
// VGPR-starved staging (68 VGPRs => serialized global->reg->LDS rounds) and
// one-shot blocks (loads in flight only during a short front phase).
//
// R3: persistent 8-tile blocks, double-buffered LDS, global_load_lds(16B)
// direct staging, counted vmcnt waits (never 0 in the loop), single wave per
// block => NO barriers (no vmcnt(0) drain). Linear LDS (required by
// global_load_lds) + XOR swizzle applied on BOTH sides: pre-swizzled global
// source address feeds the linear DMA writes; all ds_read/ds_write use the
// same swizzled index => every b128 LDS phase is at the conflict-free 8-clk
// minimum. Lane63 -> lane0 __shfl carries the exact filter state across
// tiles (only tile 0 needs a 64-sample global halo for its warm-up).
// LDS = 2*16KB + 256B = 33KB => 4 blocks/CU, 1024 blocks all resident.

constexpr int T_LEN   = 1 << 20;                 // samples per channel
constexpr int L_G     = 16;                      // granules (float4) per 64-sample chunk
constexpr int THREADS = 64;                      // one wave per block
constexpr int TILE_G  = THREADS * L_G;           // 1024 granules = 16 KiB
constexpr int NT      = 8;                       // tiles per block
constexpr int GRAN_PER_BLOCK  = NT * TILE_G;     // 8192
constexpr int GRAN_PER_CHAN   = T_LEN / 4;       // 262144
constexpr int BLOCKS_PER_CHAN = GRAN_PER_CHAN / GRAN_PER_BLOCK;  // 32

// Counted vmcnt wait. Robust: guarantees everything OLDER than the N newest
// vmem ops is complete (in-order counting), and >=N ops are always issued
// between a tile's loads and its wait (16 stores + 16 prefetch loads).
#define WAITVM(N) asm volatile("s_waitcnt vmcnt(" #N ")" ::: "memory")
// Compiler fence + LDS drain between cross-lane LDS phases (same-wave DS is
// in-order in HW; the fence stops the compiler from interleaving phases it
// believes are thread-independent).
#define LDSFENCE() asm volatile("s_waitcnt lgkmcnt(0)" ::: "memory")

__device__ __forceinline__ int swz(int row, int col) {
    // logical (row, col) -> LDS granule index (XOR swizzle inside each row)
    return (row << 4) | (col ^ (row & 15));
}

__device__ __forceinline__ void async_tile_load(const float4* __restrict__ x4,
                                                size_t gbase, float4* ldsbuf,
                                                int t)
{
    // 16 x global_load_lds_dwordx4: LDS dest is wave-uniform base + lane*16
    // (linear). Source address is per-lane and pre-swizzled so that data for
    // logical (row,col) lands at LDS position swz(row,col).
#pragma unroll
    for (int i = 0; i < 16; ++i) {
        const int p   = (i << 6) | t;       // linear LDS granule this lane fills
        const int row = p >> 4;
        const int src = swz(row, p & 15);   // involution: same map both ways
        __builtin_amdgcn_global_load_lds(
            (const __attribute__((address_space(1))) void*)(x4 + gbase + src),
            (__attribute__((address_space(3))) void*)(ldsbuf + (i << 6)),
            16, 0, 0);
    }
}

__global__ __launch_bounds__(THREADS, 1) void peak_kernel(
    const float4* __restrict__ x4,
    const float* __restrict__ p_freq_raw,
    const float* __restrict__ p_q_raw,
    const float* __restrict__ p_gain,
    float4* __restrict__ y4)
{
    __shared__ float4 buf[2][TILE_G];   // double-buffered x/y tile (swizzled)
    __shared__ float4 halo0[L_G];       // warm-up chunk for tile 0, thread 0

    const int t = threadIdx.x;
    const size_t tb0 = (size_t)blockIdx.x * GRAN_PER_BLOCK;
    const bool chan_start = (blockIdx.x % BLOCKS_PER_CHAN) == 0;

    // ---- coefficients (cheap scalar math; overlaps with loads) ----
    float fraw = p_freq_raw[0];
    float qraw = p_q_raw[0];
    float gdb  = p_gain[0];

    float sfreq = 1.0f / (1.0f + __expf(-fraw));
    float freq  = sfreq * (17500.0f - 33.0f) + 33.0f;
    float sq    = 1.0f / (1.0f + __expf(-qraw));
    float Q     = sq * (20.0f - 0.2f) + 0.2f;

    float w0    = 6.283185307179586f * freq / 44100.0f;
    float A     = expf(gdb * 0.05756462732485114f);   // 10^(g/40)
    float sw    = sinf(w0);
    float cw    = cosf(w0);
    float alpha = sw / (2.0f * Q);

    float inv_a0 = 1.0f / (1.0f + alpha / A);
    float b0  = (1.0f + alpha * A) * inv_a0;
    float b1  = (-2.0f * cw) * inv_a0;
    float b2  = (1.0f - alpha * A) * inv_a0;
    float na1 = -b1;
    float na2 = -((1.0f - alpha / A) * inv_a0);

    // ---- prologue: halo for tile 0, then issue tile-0 loads ----
    float4 h0 = make_float4(0.f, 0.f, 0.f, 0.f);
    if (t < L_G && !chan_start) h0 = x4[tb0 - L_G + t];   // oldest vmem op

    async_tile_load(x4, tb0, &buf[0][0], t);              // loads_0 (16 ops)

    if (t < L_G) halo0[t] = h0;   // compiler waits only for h0 (counted)

    float s1 = 0.f, s2 = 0.f;     // running DF2T state (exact after tile 0)

#pragma unroll 1
    for (int k = 0; k < NT; ++k) {
        const int    bsel = k & 1;
        const size_t gb   = tb0 + (size_t)k * TILE_G;

        // prefetch next tile into the other buffer BEFORE waiting
        if (k + 1 < NT)
            async_tile_load(x4, gb + TILE_G, &buf[bsel ^ 1][0], t);

        // wait for THIS tile's loads only:
        //   k==0:   outstanding = loads_0 + loads_1           -> vmcnt(16)
        //   middle: loads_k + stores_{k-1} + loads_{k+1}      -> vmcnt(32)
        //   last:   loads_{NT-1} + stores_{NT-2}              -> vmcnt(16)
        if (k == 0 || k == NT - 1) { WAITVM(16); } else { WAITVM(32); }

        // exact state carry: lane 63's end state -> lane 0 of next tile
        const float cs1 = __shfl(s1, 63);
        const float cs2 = __shfl(s2, 63);

        // ---- warm-up (64 samples, discard outputs) ----
        // thread t>0: previous chunk = row t-1 of this tile
        // thread 0, k==0: halo0; thread 0, k>0: dummy row 0 (replaced by carry)
        const float4* wbase;
        int wmask;
        if (t == 0) { wbase = (k == 0) ? &halo0[0] : &buf[bsel][0]; wmask = 0; }
        else        { wbase = &buf[bsel][(t - 1) << 4]; wmask = (t - 1) & 15; }

        float a1s = 0.f, a2s = 0.f;
#pragma unroll
        for (int j = 0; j < 16; ++j) {
            float4 xv = wbase[j ^ wmask];
#pragma unroll
            for (int q = 0; q < 4; ++q) {
                float xt = (&xv.x)[q];
                float yv = fmaf(b0, xt, a1s);
                a1s = fmaf(b1, xt, a2s);
                a1s = fmaf(na1, yv, a1s);
                a2s = xt * b2;
                a2s = fmaf(na2, yv, a2s);
            }
        }
        {
            const bool carry = (t == 0) && (k > 0);
            s1 = carry ? cs1 : a1s;
            s2 = carry ? cs2 : a2s;
        }

        LDSFENCE();   // all warm-up reads done before rows are overwritten

        // ---- main pass: own chunk (row t), overwrite x with y in place ----
        {
            float4* mbase = &buf[bsel][t << 4];
            const int mmask = t & 15;
#pragma unroll
            for (int j = 0; j < 16; ++j) {
                float4 xv = mbase[j ^ mmask];
                float4 ov;
#pragma unroll
                for (int q = 0; q < 4; ++q) {
                    float xt = (&xv.x)[q];
                    float yv = fmaf(b0, xt, s1);
                    s1 = fmaf(b1, xt, s2);
                    s1 = fmaf(na1, yv, s1);
                    s2 = xt * b2;
                    s2 = fmaf(na2, yv, s2);
                    (&ov.x)[q] = yv;
                }
                mbase[j ^ mmask] = ov;
            }
        }

        LDSFENCE();   // y fully in LDS before cross-lane store reads

        // ---- coalesced LDS -> global (exactly 16 store ops: the wait
        //      arithmetic above depends on this count) ----
#pragma unroll
        for (int i = 0; i < 16; ++i) {
            const int p   = (i << 6) | t;
            const int row = p >> 4;
            y4[gb + p] = buf[bsel][swz(row, p & 15)];
        }
    }
}

extern "C" void kernel_launch(void* const* d_in, const int* in_sizes, int n_in,
                              void* d_out, int out_size, void* d_ws, size_t ws_size,
                              hipStream_t stream)
{
    const float4* x4 = (const float4*)d_in[0];
    const float*  fr = (const float*)d_in[1];
    const float*  qr = (const float*)d_in[2];
    const float*  gn = (const float*)d_in[3];
    float4*       y4 = (float4*)d_out;

    int n_channels = in_sizes[0] / T_LEN;                 // 32
    int n_blocks   = n_channels * BLOCKS_PER_CHAN;        // 1024

    hipLaunchKernelGGL(peak_kernel, dim3(n_blocks), dim3(THREADS), 0, stream,
                       x4, fr, qr, gn, y4);
}